// Round 17
// baseline (59.109 us; speedup 1.0000x reference)
//
#include <hip/hip_runtime.h>
#include <hip/hip_bf16.h>
#include <math.h>

#define SEQ 8192
#define DIN 768
#define DOUT 64
#define QSCALE 0.1803368801111214f   // 0.125 * log2(e)

typedef __attribute__((ext_vector_type(8))) short short8;
typedef __attribute__((ext_vector_type(4))) short short4v;
typedef __attribute__((ext_vector_type(4))) float floatx4;
typedef __attribute__((ext_vector_type(2))) unsigned int uint2v;

// ---------------------------------------------------------------------------
// helpers
// ---------------------------------------------------------------------------
__device__ __forceinline__ void gload16(const void* g, void* l) {
    __builtin_amdgcn_global_load_lds(
        (const __attribute__((address_space(1))) unsigned int*)g,
        (__attribute__((address_space(3))) unsigned int*)l, 16, 0, 0);
}

__device__ __forceinline__ unsigned pack2(float a, float b) {
    __hip_bfloat162 h = __float22bfloat162_rn(make_float2(a, b));
    return *(unsigned*)&h;
}

__device__ __forceinline__ unsigned short bfbits(float f) {
    __hip_bfloat16 h = __float2bfloat16(f);
    return *(unsigned short*)&h;
}

__device__ __forceinline__ float bf2f(unsigned short u) {
    unsigned v = ((unsigned)u) << 16;
    return *(float*)&v;
}

__device__ __forceinline__ float exp2r(float x) {
#if __has_builtin(__builtin_amdgcn_exp2f)
    return __builtin_amdgcn_exp2f(x);
#else
    float r; asm("v_exp_f32 %0, %1" : "=v"(r) : "v"(x)); return r;
#endif
}

__device__ __forceinline__ floatx4 mfma16(short4v a, short4v b, floatx4 c) {
#if __has_builtin(__builtin_amdgcn_mfma_f32_16x16x16bf16_1k)
    return __builtin_amdgcn_mfma_f32_16x16x16bf16_1k(a, b, c, 0, 0, 0);
#else
    asm("v_mfma_f32_16x16x16_bf16 %0, %1, %2, %0" : "+v"(c) : "v"(a), "v"(b));
    return c;
#endif
}

// barrier that is ALSO a compiler memory fence (raw builtin is not)
#define BAR()       asm volatile("s_barrier" ::: "memory")
#define WAIT_VM4()  asm volatile("s_waitcnt vmcnt(4)" ::: "memory")
#define WAIT_VM0()  asm volatile("s_waitcnt vmcnt(0)" ::: "memory")

// ---------------------------------------------------------------------------
// Kernel 1: QKV projection via MFMA (round-12 version, frozen).
// Inline W fp32->bf16, 3-deep x prefetch, 512 thr, 32 rows/block, grid 256.
// Out: qbf [SEQ][64] (pre-scaled QSCALE), kbf [SEQ][64], vtbf [64][SEQ].
// LDS swizzle: byte(R,c) = R*128 + (((c>>3) ^ (R&7))<<4) + (c&7)*2
// ---------------------------------------------------------------------------
__global__ __launch_bounds__(512) void qkv_mfma(
    const float* __restrict__ x,
    const float* __restrict__ Wq, const float* __restrict__ Wk,
    const float* __restrict__ Wv,
    unsigned short* __restrict__ qbf, unsigned short* __restrict__ kbf,
    unsigned short* __restrict__ vtbf)
{
    __shared__ __align__(16) unsigned char xs[2][32 * 128];    // 2 x 4 KB
    __shared__ __align__(16) unsigned char wsm[2][192 * 128];  // 2 x 24 KB

    const int t = threadIdx.x;          // 0..511
    const int l = t & 63;
    const int wid = t >> 6;             // 0..7
    const int h = wid & 1;              // row-tile (16 rows)
    const int ntb = (wid >> 1) * 3;     // nt triple base {0,3,6,9}
    const int g = l >> 4;
    const int q4 = l & 15;
    const int row0 = blockIdx.x * 32;

    const int wrow0 = (t >> 3) * 3;     // 0,3,...,189
    const int wc8   = t & 7;            // 8-col chunk
    const int xrow = t >> 4;            // 0..31
    const int xc4  = t & 15;            // 4-col chunk

    float4 wreg[3][2];
    float4 xA, xB, x0;

#define WLOAD(k0)                                                             \
    {                                                                         \
        _Pragma("unroll")                                                     \
        for (int rr = 0; rr < 3; ++rr) {                                      \
            const int row = wrow0 + rr;                                       \
            const float* wp = (row < 64)  ? &Wq[(size_t)row * DIN]            \
                           : (row < 128) ? &Wk[(size_t)(row - 64) * DIN]      \
                                         : &Wv[(size_t)(row - 128) * DIN];    \
            wreg[rr][0] = *(const float4*)&wp[(k0) + wc8 * 8];                \
            wreg[rr][1] = *(const float4*)&wp[(k0) + wc8 * 8 + 4];            \
        }                                                                     \
    }
#define WWRITE(buf)                                                           \
    {                                                                         \
        _Pragma("unroll")                                                     \
        for (int rr = 0; rr < 3; ++rr) {                                      \
            const int row = wrow0 + rr;                                       \
            uint4 v;                                                          \
            v.x = pack2(wreg[rr][0].x, wreg[rr][0].y);                        \
            v.y = pack2(wreg[rr][0].z, wreg[rr][0].w);                        \
            v.z = pack2(wreg[rr][1].x, wreg[rr][1].y);                        \
            v.w = pack2(wreg[rr][1].z, wreg[rr][1].w);                        \
            *(uint4*)&wsm[buf][row * 128 + ((wc8 ^ (row & 7)) << 4)] = v;     \
        }                                                                     \
    }
#define XLOAD(dst, k0)                                                        \
    dst = *(const float4*)&x[(size_t)(row0 + xrow) * DIN + (k0) + xc4 * 4];
#define XWRITE(buf, src)                                                      \
    {                                                                         \
        uint2 v2;                                                             \
        v2.x = pack2(src.x, src.y);                                           \
        v2.y = pack2(src.z, src.w);                                           \
        const int half = xc4 & 1, slq = xc4 >> 1;                             \
        *(uint2*)&xs[buf][xrow * 128 + ((slq ^ (xrow & 7)) << 4) + half * 8] = v2; \
    }

    floatx4 acc[3];
#pragma unroll
    for (int i = 0; i < 3; ++i) acc[i] = (floatx4){0.f, 0.f, 0.f, 0.f};

    // ---- prologue: chunk 0 staged; x chunks 1,2 + W chunk 1 in flight ----
    WLOAD(0)
    XLOAD(x0, 0)
    XLOAD(xA, 64)       // chunk 1 (odd)
    XLOAD(xB, 128)      // chunk 2 (even)
    WWRITE(0)
    XWRITE(0, x0)
    WLOAD(64)           // W chunk 1 into wreg
    __syncthreads();

#pragma unroll
    for (int kc = 0; kc < 12; ++kc) {
        const int cur = kc & 1;

        // ---- compute chunk kc from buf[cur] ----
        __builtin_amdgcn_s_setprio(1);
#pragma unroll
        for (int ks = 0; ks < 2; ++ks) {
            const int sl = g + 4 * ks;
            const int Rx = h * 16 + q4;
            const short8 a = *(const short8*)&xs[cur][Rx * 128 + ((sl ^ (Rx & 7)) << 4)];
#pragma unroll
            for (int j = 0; j < 3; ++j) {
                const int Rw = (ntb + j) * 16 + q4;
                const short8 b = *(const short8*)&wsm[cur][Rw * 128 + ((sl ^ (Rw & 7)) << 4)];
                acc[j] = __builtin_amdgcn_mfma_f32_16x16x32_bf16(a, b, acc[j], 0, 0, 0);
            }
        }
        __builtin_amdgcn_s_setprio(0);

        // ---- tail: write chunk kc+1 (regs held 2 iters), reload ahead ----
        if (kc + 1 < 12) {
            WWRITE(cur ^ 1)                       // W(kc+1)
            if ((kc + 1) & 1) { XWRITE(cur ^ 1, xA) } else { XWRITE(cur ^ 1, xB) }
            if (kc + 2 < 12) WLOAD((kc + 2) * 64) // W(kc+2), consumed next tail
            if (kc + 3 < 12) {
                if ((kc + 3) & 1) { XLOAD(xA, (kc + 3) * 64) }
                else             { XLOAD(xB, (kc + 3) * 64) }
            }
        }
        __syncthreads();
    }

    // epilogue: C layout row=(l>>4)*4+reg, col=l&15
    const int rb = row0 + h * 16 + (g << 2);
#pragma unroll
    for (int j = 0; j < 3; ++j) {
        const int nt = ntb + j;
#pragma unroll
        for (int r = 0; r < 4; ++r) {
            const float v = acc[j][r];
            const int R = rb + r;
            if (nt < 4) {
                qbf[(size_t)R * 64 + nt * 16 + q4] = bfbits(v * QSCALE);
            } else if (nt < 8) {
                kbf[(size_t)R * 64 + (nt - 4) * 16 + q4] = bfbits(v);
            } else {
                vtbf[(size_t)((nt - 8) * 16 + q4) * SEQ + R] = bfbits(v);
            }
        }
    }
#undef WLOAD
#undef WWRITE
#undef XLOAD
#undef XWRITE
}

// ---------------------------------------------------------------------------
// Kernel 2: flash attention (round-16 version, frozen).
// 32 q-rows/wave, fixed-m softmax, counted-vmcnt dbuf, bf16 partials.
// grid (SEQ/128, nsplit), 256 thr (4 waves x 32 q-rows).
// ---------------------------------------------------------------------------
__global__ __launch_bounds__(256, 4) void flash_mfma(
    const unsigned short* __restrict__ qbf,
    const unsigned short* __restrict__ kbf,
    const unsigned short* __restrict__ vtbf,
    void* __restrict__ opart,    // bf16 [nsplit][SEQ][64], or fp32 out (direct)
    float* __restrict__ ml,      // [nsplit][SEQ][2]
    int nsplit, int direct)
{
    __shared__ __align__(16) unsigned char lds[32768];
    unsigned char* lkb = lds;              // 2 x 8 KB (dbuf K)
    unsigned char* lvb = lds + 16384;      // 2 x 8 KB (dbuf V^T)

    const int t = threadIdx.x;
    const int l = t & 63;
    const int g = l >> 4;
    const int q4 = l & 15;
    const int wid = t >> 6;
    const int row0 = blockIdx.x * 128;
    const int split = blockIdx.y;
    const int chunk = SEQ / nsplit;
    const int kbeg = split * chunk;
    const int NT = chunk / 64;

#define ISSUE_KV(buf, kt)                                                     \
    {                                                                         \
        const int Rr = l >> 3;                                                \
        const int sl = (l & 7) ^ Rr;                                          \
        _Pragma("unroll")                                                     \
        for (int ss = 0; ss < 2; ++ss) {                                      \
            const int s = wid * 2 + ss;                                       \
            const int R = 8 * s + Rr;                                         \
            gload16(&kbf[(size_t)((kt) + R) * 64 + sl * 8],                   \
                    lkb + (buf) * 8192 + s * 1024);                           \
            gload16(&vtbf[(size_t)R * SEQ + (kt) + sl * 8],                   \
                    lvb + (buf) * 8192 + s * 1024);                           \
        }                                                                     \
    }

    // Q fragments: wave owns q rows [row0 + wid*32, +32)
    short8 qf[2][2];
#pragma unroll
    for (int qt = 0; qt < 2; ++qt)
#pragma unroll
        for (int ks = 0; ks < 2; ++ks)
            qf[qt][ks] = *(const short8*)&qbf[
                (size_t)(row0 + wid * 32 + qt * 16 + q4) * 64 + (g + 4 * ks) * 8];

    // prologue: tiles 0 and 1 in flight
    ISSUE_KV(0, kbeg)
    if (NT > 1) ISSUE_KV(1, kbeg + 64)

    floatx4 oacc[2][4];
#pragma unroll
    for (int i = 0; i < 2; ++i)
#pragma unroll
        for (int j = 0; j < 4; ++j) oacc[i][j] = (floatx4){0.f, 0.f, 0.f, 0.f};
    floatx4 l_acc[2] = {(floatx4){0.f, 0.f, 0.f, 0.f},
                        (floatx4){0.f, 0.f, 0.f, 0.f}};

    int cur = 0;
    for (int tt = 0; tt < NT; ++tt) {
        if (tt + 1 < NT) { WAIT_VM4(); } else { WAIT_VM0(); }
        BAR();   // tile tt staged for all waves

        const unsigned char* lk = lkb + cur * 8192;
        const unsigned char* lv = lvb + cur * 8192;

        // ---- S^T = K Q^T ----
        floatx4 sacc[2][4];
#pragma unroll
        for (int i = 0; i < 2; ++i)
#pragma unroll
            for (int j = 0; j < 4; ++j) sacc[i][j] = (floatx4){0.f, 0.f, 0.f, 0.f};
        __builtin_amdgcn_s_setprio(1);
#pragma unroll
        for (int ks = 0; ks < 2; ++ks) {
            const int sl = g + 4 * ks;
#pragma unroll
            for (int nt = 0; nt < 4; ++nt) {
                const int R = nt * 16 + q4;
                const short8 kf = *(const short8*)&lk[R * 128 + ((sl ^ (R & 7)) << 4)];
                sacc[0][nt] = __builtin_amdgcn_mfma_f32_16x16x32_bf16(kf, qf[0][ks], sacc[0][nt], 0, 0, 0);
                sacc[1][nt] = __builtin_amdgcn_mfma_f32_16x16x32_bf16(kf, qf[1][ks], sacc[1][nt], 0, 0, 0);
            }
        }
        __builtin_amdgcn_s_setprio(0);

        // ---- fixed-m softmax: p = 2^s directly ----
        floatx4 pv[2][4];
#pragma unroll
        for (int qt = 0; qt < 2; ++qt) {
#pragma unroll
            for (int nt = 0; nt < 4; ++nt) {
                pv[qt][nt][0] = exp2r(sacc[qt][nt][0]);
                pv[qt][nt][1] = exp2r(sacc[qt][nt][1]);
                pv[qt][nt][2] = exp2r(sacc[qt][nt][2]);
                pv[qt][nt][3] = exp2r(sacc[qt][nt][3]);
            }
            l_acc[qt] += (pv[qt][0] + pv[qt][1]) + (pv[qt][2] + pv[qt][3]);
        }

        // ---- O^T += V^T P^T ----
        __builtin_amdgcn_s_setprio(1);
#pragma unroll
        for (int kb = 0; kb < 4; ++kb) {
            const short4v pb0 = __builtin_bit_cast(short4v,
                (uint2v){pack2(pv[0][kb][0], pv[0][kb][1]),
                         pack2(pv[0][kb][2], pv[0][kb][3])});
            const short4v pb1 = __builtin_bit_cast(short4v,
                (uint2v){pack2(pv[1][kb][0], pv[1][kb][1]),
                         pack2(pv[1][kb][2], pv[1][kb][3])});
            const int sl = kb * 2 + (g >> 1);
#pragma unroll
            for (int dt = 0; dt < 4; ++dt) {
                const int R = dt * 16 + q4;
                const short4v a = *(const short4v*)&lv[R * 128 +
                    ((sl ^ (R & 7)) << 4) + ((g & 1) << 3)];
                oacc[0][dt] = mfma16(a, pb0, oacc[0][dt]);
                oacc[1][dt] = mfma16(a, pb1, oacc[1][dt]);
            }
        }
        __builtin_amdgcn_s_setprio(0);

        BAR();   // all waves done reading buf[cur]
        if (tt + 2 < NT) ISSUE_KV(cur, kbeg + (tt + 2) * 64)
        cur ^= 1;
    }

    // ---- one-time cross-lane l reduction ----
    float l_run[2];
#pragma unroll
    for (int qt = 0; qt < 2; ++qt) {
        float s = (l_acc[qt][0] + l_acc[qt][1]) + (l_acc[qt][2] + l_acc[qt][3]);
        s += __shfl_xor(s, 16);
        s += __shfl_xor(s, 32);
        l_run[qt] = s;
    }

    if (!direct && g == 0) {
#pragma unroll
        for (int qt = 0; qt < 2; ++qt) {
            const size_t mrow = (size_t)split * SEQ + row0 + wid * 32 + qt * 16 + q4;
            ml[mrow * 2 + 0] = 0.0f;     // fixed m
            ml[mrow * 2 + 1] = l_run[qt];
        }
    }

    if (direct) {
        // ---- fp32 two-pass transpose, full 256B-row stores ----
        float* trans = (float*)lds;       // [64][68]
        float* outbase = (float*)opart;
#pragma unroll
        for (int qt = 0; qt < 2; ++qt) {
            __syncthreads();
            {
                const int r = wid * 16 + q4;
                const float sc = 1.0f / l_run[qt];
#pragma unroll
                for (int dt = 0; dt < 4; ++dt)
                    *(floatx4*)&trans[r * 68 + dt * 16 + g * 4] = oacc[qt][dt] * sc;
            }
            __syncthreads();
#pragma unroll
            for (int it = 0; it < 4; ++it) {
                const int r = it * 16 + (t >> 4);
                const int qrow = row0 + ((r >> 4) << 5) + qt * 16 + (r & 15);
                const floatx4 v = *(const floatx4*)&trans[r * 68 + (t & 15) * 4];
                *(floatx4*)&outbase[(size_t)qrow * 64 + (t & 15) * 4] = v;
            }
        }
    } else {
        // ---- bf16 two-pass transpose, full 128B-row stores ----
        unsigned short* transb = (unsigned short*)lds;   // [64][72] bf16
        unsigned short* outb = (unsigned short*)opart + (size_t)split * SEQ * 64;
#pragma unroll
        for (int qt = 0; qt < 2; ++qt) {
            __syncthreads();
            {
                const int r = wid * 16 + q4;
#pragma unroll
                for (int dt = 0; dt < 4; ++dt) {
                    uint2 v2;
                    v2.x = pack2(oacc[qt][dt][0], oacc[qt][dt][1]);
                    v2.y = pack2(oacc[qt][dt][2], oacc[qt][dt][3]);
                    *(uint2*)&transb[r * 72 + dt * 16 + g * 4] = v2;
                }
            }
            __syncthreads();
#pragma unroll
            for (int it = 0; it < 2; ++it) {
                const int r = it * 32 + (t >> 3);
                const int qrow = row0 + ((r >> 4) << 5) + qt * 16 + (r & 15);
                const short8 v = *(const short8*)&transb[r * 72 + (t & 7) * 8];
                *(short8*)&outb[(size_t)qrow * 64 + (t & 7) * 8] = v;
            }
        }
    }
#undef ISSUE_KV
}

// ---------------------------------------------------------------------------
// Kernel 3: combine bf16 split partials (m == 0 everywhere -> plain sums).
// out = (Σ O_s) / (Σ l_s), fp32 accumulate.  8 outputs / thread.
// ---------------------------------------------------------------------------
__global__ __launch_bounds__(256) void combine_kernel(
    const unsigned short* __restrict__ opart, const float* __restrict__ ml,
    float* __restrict__ out, int nsplit)
{
    const int i8 = (blockIdx.x * 256 + threadIdx.x) * 8;
    if (i8 >= SEQ * DOUT) return;
    const int row = i8 >> 6;

    float denom = 0.f;
    float acc[8] = {0.f, 0.f, 0.f, 0.f, 0.f, 0.f, 0.f, 0.f};
    for (int s = 0; s < nsplit; ++s) {
        denom += ml[((size_t)s * SEQ + row) * 2 + 1];
        const short8 v = *(const short8*)&opart[(size_t)s * SEQ * DOUT + i8];
#pragma unroll
        for (int j = 0; j < 8; ++j)
            acc[j] += bf2f((unsigned short)v[j]);
    }
    const float inv = 1.0f / denom;
    floatx4 o0 = {acc[0] * inv, acc[1] * inv, acc[2] * inv, acc[3] * inv};
    floatx4 o1 = {acc[4] * inv, acc[5] * inv, acc[6] * inv, acc[7] * inv};
    *(floatx4*)&out[i8] = o0;
    *(floatx4*)&out[i8 + 4] = o1;
}

// ---------------------------------------------------------------------------
extern "C" void kernel_launch(void* const* d_in, const int* in_sizes, int n_in,
                              void* d_out, int out_size, void* d_ws, size_t ws_size,
                              hipStream_t stream)
{
    const float* x  = (const float*)d_in[0];
    const float* Wq = (const float*)d_in[1];
    const float* Wk = (const float*)d_in[2];
    const float* Wv = (const float*)d_in[3];
    float* out = (float*)d_out;
    unsigned char* ws = (unsigned char*)d_ws;

    const size_t qkv_b = (size_t)SEQ * 64 * 2;
    size_t off = 0;
    unsigned short* qbf  = (unsigned short*)(ws + off); off += qkv_b;
    unsigned short* kbf  = (unsigned short*)(ws + off); off += qkv_b;
    unsigned short* vtbf = (unsigned short*)(ws + off); off += qkv_b;

    // per split: bf16 opart (1 MB) + fp32 ml (64 KB)
    const size_t per_split = (size_t)SEQ * 64 * 2 + (size_t)SEQ * 2 * 4;
    // nsplit=32 -> grid 2048 blocks -> 5 resident blocks/CU (LDS-capped),
    // 20 waves/CU vs 16 at nsplit=16 (grid was the residency limiter).
    int nsplit = 0;
    if      (ws_size >= off + 32 * per_split) nsplit = 32;
    else if (ws_size >= off + 16 * per_split) nsplit = 16;
    else if (ws_size >= off + 8 * per_split)  nsplit = 8;
    else if (ws_size >= off + 4 * per_split)  nsplit = 4;
    else if (ws_size >= off + 2 * per_split)  nsplit = 2;

    qkv_mfma<<<SEQ / 32, 512, 0, stream>>>(x, Wq, Wk, Wv, qbf, kbf, vtbf);

    if (nsplit == 0) {
        flash_mfma<<<dim3(SEQ / 128, 1), 256, 0, stream>>>(
            qbf, kbf, vtbf, (void*)out, nullptr, 1, 1);
    } else {
        unsigned short* opart = (unsigned short*)(ws + off);
        float* mlp = (float*)(ws + off + (size_t)nsplit * SEQ * 64 * 2);
        flash_mfma<<<dim3(SEQ / 128, nsplit), 256, 0, stream>>>(
            qbf, kbf, vtbf, (void*)opart, mlp, nsplit, 0);
        combine_kernel<<<SEQ * DOUT / 8 / 256, 256, 0, stream>>>(
            opart, mlp, out, nsplit);
    }
}

// Round 18
// 57.192 us; speedup vs baseline: 1.0335x; 1.0335x over previous
//
#include <hip/hip_runtime.h>
#include <hip/hip_bf16.h>
#include <math.h>

#define SEQ 8192
#define DIN 768
#define DOUT 64
#define QSCALE 0.1803368801111214f   // 0.125 * log2(e)

typedef __attribute__((ext_vector_type(8))) short short8;
typedef __attribute__((ext_vector_type(4))) short short4v;
typedef __attribute__((ext_vector_type(4))) float floatx4;
typedef __attribute__((ext_vector_type(2))) unsigned int uint2v;

// ---------------------------------------------------------------------------
// helpers
// ---------------------------------------------------------------------------
__device__ __forceinline__ void gload16(const void* g, void* l) {
    __builtin_amdgcn_global_load_lds(
        (const __attribute__((address_space(1))) unsigned int*)g,
        (__attribute__((address_space(3))) unsigned int*)l, 16, 0, 0);
}

__device__ __forceinline__ unsigned pack2(float a, float b) {
    __hip_bfloat162 h = __float22bfloat162_rn(make_float2(a, b));
    return *(unsigned*)&h;
}

__device__ __forceinline__ unsigned short bfbits(float f) {
    __hip_bfloat16 h = __float2bfloat16(f);
    return *(unsigned short*)&h;
}

__device__ __forceinline__ float bf2f(unsigned short u) {
    unsigned v = ((unsigned)u) << 16;
    return *(float*)&v;
}

__device__ __forceinline__ float exp2r(float x) {
#if __has_builtin(__builtin_amdgcn_exp2f)
    return __builtin_amdgcn_exp2f(x);
#else
    float r; asm("v_exp_f32 %0, %1" : "=v"(r) : "v"(x)); return r;
#endif
}

__device__ __forceinline__ floatx4 mfma16(short4v a, short4v b, floatx4 c) {
#if __has_builtin(__builtin_amdgcn_mfma_f32_16x16x16bf16_1k)
    return __builtin_amdgcn_mfma_f32_16x16x16bf16_1k(a, b, c, 0, 0, 0);
#else
    asm("v_mfma_f32_16x16x16_bf16 %0, %1, %2, %0" : "+v"(c) : "v"(a), "v"(b));
    return c;
#endif
}

// barrier that is ALSO a compiler memory fence (raw builtin is not)
#define BAR()       asm volatile("s_barrier" ::: "memory")
#define CFENCE()    asm volatile("" ::: "memory")
#define WAIT_VM8()  asm volatile("s_waitcnt vmcnt(8)" ::: "memory")
#define WAIT_VM6()  asm volatile("s_waitcnt vmcnt(6)" ::: "memory")
#define WAIT_VM4()  asm volatile("s_waitcnt vmcnt(4)" ::: "memory")
#define WAIT_VM0()  asm volatile("s_waitcnt vmcnt(0)" ::: "memory")
#define WAIT_LGKM() asm volatile("s_waitcnt lgkmcnt(0)" ::: "memory")

// ---------------------------------------------------------------------------
// Kernel 0: W (3 x [64][768] fp32) -> wbf [192][768] bf16 row-major
// ---------------------------------------------------------------------------
__global__ __launch_bounds__(256) void prep_w(
    const float* __restrict__ Wq, const float* __restrict__ Wk,
    const float* __restrict__ Wv, unsigned short* __restrict__ wbf)
{
    const int i = blockIdx.x * 256 + threadIdx.x;
    const int base = i * 8;
    const int row = base / DIN;
    const int k = base % DIN;
    const float* src = (row < 64)  ? &Wq[(size_t)row * DIN + k]
                     : (row < 128) ? &Wk[(size_t)(row - 64) * DIN + k]
                                   : &Wv[(size_t)(row - 128) * DIN + k];
    const float4 f0 = *(const float4*)src;
    const float4 f1 = *(const float4*)(src + 4);
    uint4 v;
    v.x = pack2(f0.x, f0.y);
    v.y = pack2(f0.z, f0.w);
    v.z = pack2(f1.x, f1.y);
    v.w = pack2(f1.z, f1.w);
    *(uint4*)&wbf[base] = v;
}

// ---------------------------------------------------------------------------
// Kernel 1: QKV projection via MFMA.  256 thr (4 waves), 32 rows/block,
// grid 256, BK=64.  W staged bf16 via global_load_lds (pre-swizzled src,
// half the L2 bytes of fp32, zero staging VALU); x staged via 3-deep
// register prefetch (HBM stream).  Counted-vmcnt, fence-pinned regions:
//   top of kc needs W(kc) landed; provably-newer ops = tail(kc-1) region
//   = W(kc+1) 6 + x 2 = 8  ->  VM8 (kc<=9), VM6 (kc==10), VM0 (kc==11).
// Out: qbf [SEQ][64] (pre-scaled QSCALE), kbf [SEQ][64], vtbf [64][SEQ].
// LDS swizzle: byte(R,c) = R*128 + (((c>>3) ^ (R&7))<<4) + (c&7)*2
// ---------------------------------------------------------------------------
__global__ __launch_bounds__(256) void qkv_mfma(
    const float* __restrict__ x, const unsigned short* __restrict__ wbf,
    unsigned short* __restrict__ qbf, unsigned short* __restrict__ kbf,
    unsigned short* __restrict__ vtbf)
{
    __shared__ __align__(16) unsigned char xs[2][32 * 128];    // 2 x 4 KB
    __shared__ __align__(16) unsigned char wsm[2][192 * 128];  // 2 x 24 KB

    const int t = threadIdx.x;
    const int l = t & 63;
    const int wid = t >> 6;            // 0..3
    const int h = wid & 1;             // row half (16 rows)
    const int ntb = (wid >> 1) * 6;    // output-tile base (6 tiles)
    const int g = l >> 4;
    const int q4 = l & 15;
    const int row0 = blockIdx.x * 32;

    const int Rx_st = t >> 3;          // x-stage row 0..31
    const int slx   = t & 7;           // x-stage slot
    const int Rr    = l >> 3;          // W-stage sub-row 0..7
    const int sld   = (l & 7) ^ Rr;    // W-stage pre-swizzled source slot

    floatx4 acc[6];
#pragma unroll
    for (int i = 0; i < 6; ++i) acc[i] = (floatx4){0.f, 0.f, 0.f, 0.f};

#define ISSUE_W(buf, k0)                                                      \
    {                                                                         \
        _Pragma("unroll")                                                     \
        for (int ss = 0; ss < 6; ++ss) {                                      \
            const int s = wid * 6 + ss;            /* 0..23 */                \
            const int Rw = 8 * s + Rr;             /* 0..191 */               \
            gload16(&wbf[(size_t)Rw * DIN + (k0) + sld * 8], &wsm[buf][s * 1024]); \
        }                                                                     \
    }
#define LOAD_X(da, db, k0)                                                    \
    {                                                                         \
        da = *(const float4*)&x[(size_t)(row0 + Rx_st) * DIN + (k0) + slx * 8];     \
        db = *(const float4*)&x[(size_t)(row0 + Rx_st) * DIN + (k0) + slx * 8 + 4]; \
    }
#define WRITE_X(buf, sa, sb)                                                  \
    {                                                                         \
        uint4 v;                                                              \
        v.x = pack2(sa.x, sa.y); v.y = pack2(sa.z, sa.w);                     \
        v.z = pack2(sb.x, sb.y); v.w = pack2(sb.z, sb.w);                     \
        *(uint4*)&xs[buf][Rx_st * 128 + ((slx ^ (Rx_st & 7)) << 4)] = v;      \
    }

    // ---- prologue: W0+x0 region | fence | W1 + x1 + x2 in flight ----
    float4 xAa, xAb;   // odd chunks
    float4 xBa, xBb;   // even chunks
    {
        float4 a0, b0;
        ISSUE_W(0, 0)
        LOAD_X(a0, b0, 0)
        CFENCE();                       // pin region: W0/x0 older than rest
        ISSUE_W(1, 64)
        LOAD_X(xAa, xAb, 64)            // chunk 1 (odd)
        LOAD_X(xBa, xBb, 128)           // chunk 2 (even)
        WRITE_X(0, a0, b0)              // compiler waits a0/b0
    }

#pragma unroll
    for (int kc = 0; kc < 12; ++kc) {
        const int cur = kc & 1;
        if (kc <= 9)       { WAIT_VM8(); }
        else if (kc == 10) { WAIT_VM6(); }
        else               { WAIT_VM0(); }
        WAIT_LGKM();
        BAR();

        // ---- compute chunk kc from buf[cur] ----
        __builtin_amdgcn_s_setprio(1);
#pragma unroll
        for (int ks = 0; ks < 2; ++ks) {
            const int sl = g + 4 * ks;
            const int Rx = h * 16 + q4;
            const short8 a = *(const short8*)&xs[cur][Rx * 128 + ((sl ^ (Rx & 7)) << 4)];
#pragma unroll
            for (int j = 0; j < 6; ++j) {
                const int Rw = (ntb + j) * 16 + q4;
                const short8 b = *(const short8*)&wsm[cur][Rw * 128 + ((sl ^ (Rw & 7)) << 4)];
                acc[j] = __builtin_amdgcn_mfma_f32_16x16x32_bf16(a, b, acc[j], 0, 0, 0);
            }
        }
        __builtin_amdgcn_s_setprio(0);
        BAR();

        // ---- tail: issue W(kc+2); write x(kc+1); load x(kc+3) ----
        if (kc + 1 < 12) {
            if (kc + 2 < 12) ISSUE_W(cur, (kc + 2) * 64)
            if ((kc + 1) & 1) { WRITE_X(cur ^ 1, xAa, xAb) }
            else              { WRITE_X(cur ^ 1, xBa, xBb) }
            if (kc + 3 < 12) {
                if ((kc + 3) & 1) { LOAD_X(xAa, xAb, (kc + 3) * 64) }
                else              { LOAD_X(xBa, xBb, (kc + 3) * 64) }
            }
        }
    }

    // epilogue: C layout row=(l>>4)*4+reg, col=l&15
    const int rb = row0 + h * 16 + (g << 2);
#pragma unroll
    for (int j = 0; j < 6; ++j) {
        const int nt = ntb + j;
#pragma unroll
        for (int r = 0; r < 4; ++r) {
            const float v = acc[j][r];
            const int R = rb + r;
            if (nt < 4) {
                qbf[(size_t)R * 64 + nt * 16 + q4] = bfbits(v * QSCALE);
            } else if (nt < 8) {
                kbf[(size_t)R * 64 + (nt - 4) * 16 + q4] = bfbits(v);
            } else {
                vtbf[(size_t)((nt - 8) * 16 + q4) * SEQ + R] = bfbits(v);
            }
        }
    }
#undef ISSUE_W
#undef LOAD_X
#undef WRITE_X
}

// ---------------------------------------------------------------------------
// Kernel 2: flash attention (round-16 version, frozen).
// 32 q-rows/wave, fixed-m softmax, counted-vmcnt dbuf, bf16 partials.
// grid (SEQ/128, nsplit), 256 thr (4 waves x 32 q-rows).
// ---------------------------------------------------------------------------
__global__ __launch_bounds__(256, 4) void flash_mfma(
    const unsigned short* __restrict__ qbf,
    const unsigned short* __restrict__ kbf,
    const unsigned short* __restrict__ vtbf,
    void* __restrict__ opart,    // bf16 [nsplit][SEQ][64], or fp32 out (direct)
    float* __restrict__ ml,      // [nsplit][SEQ][2]
    int nsplit, int direct)
{
    __shared__ __align__(16) unsigned char lds[32768];
    unsigned char* lkb = lds;              // 2 x 8 KB (dbuf K)
    unsigned char* lvb = lds + 16384;      // 2 x 8 KB (dbuf V^T)

    const int t = threadIdx.x;
    const int l = t & 63;
    const int g = l >> 4;
    const int q4 = l & 15;
    const int wid = t >> 6;
    const int row0 = blockIdx.x * 128;
    const int split = blockIdx.y;
    const int chunk = SEQ / nsplit;
    const int kbeg = split * chunk;
    const int NT = chunk / 64;

#define ISSUE_KV(buf, kt)                                                     \
    {                                                                         \
        const int Rr = l >> 3;                                                \
        const int sl = (l & 7) ^ Rr;                                          \
        _Pragma("unroll")                                                     \
        for (int ss = 0; ss < 2; ++ss) {                                      \
            const int s = wid * 2 + ss;                                       \
            const int R = 8 * s + Rr;                                         \
            gload16(&kbf[(size_t)((kt) + R) * 64 + sl * 8],                   \
                    lkb + (buf) * 8192 + s * 1024);                           \
            gload16(&vtbf[(size_t)R * SEQ + (kt) + sl * 8],                   \
                    lvb + (buf) * 8192 + s * 1024);                           \
        }                                                                     \
    }

    // Q fragments: wave owns q rows [row0 + wid*32, +32)
    short8 qf[2][2];
#pragma unroll
    for (int qt = 0; qt < 2; ++qt)
#pragma unroll
        for (int ks = 0; ks < 2; ++ks)
            qf[qt][ks] = *(const short8*)&qbf[
                (size_t)(row0 + wid * 32 + qt * 16 + q4) * 64 + (g + 4 * ks) * 8];

    // prologue: tiles 0 and 1 in flight
    ISSUE_KV(0, kbeg)
    if (NT > 1) ISSUE_KV(1, kbeg + 64)

    floatx4 oacc[2][4];
#pragma unroll
    for (int i = 0; i < 2; ++i)
#pragma unroll
        for (int j = 0; j < 4; ++j) oacc[i][j] = (floatx4){0.f, 0.f, 0.f, 0.f};
    floatx4 l_acc[2] = {(floatx4){0.f, 0.f, 0.f, 0.f},
                        (floatx4){0.f, 0.f, 0.f, 0.f}};

    int cur = 0;
    for (int tt = 0; tt < NT; ++tt) {
        if (tt + 1 < NT) { WAIT_VM4(); } else { WAIT_VM0(); }
        BAR();   // tile tt staged for all waves

        const unsigned char* lk = lkb + cur * 8192;
        const unsigned char* lv = lvb + cur * 8192;

        // ---- S^T = K Q^T ----
        floatx4 sacc[2][4];
#pragma unroll
        for (int i = 0; i < 2; ++i)
#pragma unroll
            for (int j = 0; j < 4; ++j) sacc[i][j] = (floatx4){0.f, 0.f, 0.f, 0.f};
        __builtin_amdgcn_s_setprio(1);
#pragma unroll
        for (int ks = 0; ks < 2; ++ks) {
            const int sl = g + 4 * ks;
#pragma unroll
            for (int nt = 0; nt < 4; ++nt) {
                const int R = nt * 16 + q4;
                const short8 kf = *(const short8*)&lk[R * 128 + ((sl ^ (R & 7)) << 4)];
                sacc[0][nt] = __builtin_amdgcn_mfma_f32_16x16x32_bf16(kf, qf[0][ks], sacc[0][nt], 0, 0, 0);
                sacc[1][nt] = __builtin_amdgcn_mfma_f32_16x16x32_bf16(kf, qf[1][ks], sacc[1][nt], 0, 0, 0);
            }
        }
        __builtin_amdgcn_s_setprio(0);

        // ---- fixed-m softmax: p = 2^s directly ----
        floatx4 pv[2][4];
#pragma unroll
        for (int qt = 0; qt < 2; ++qt) {
#pragma unroll
            for (int nt = 0; nt < 4; ++nt) {
                pv[qt][nt][0] = exp2r(sacc[qt][nt][0]);
                pv[qt][nt][1] = exp2r(sacc[qt][nt][1]);
                pv[qt][nt][2] = exp2r(sacc[qt][nt][2]);
                pv[qt][nt][3] = exp2r(sacc[qt][nt][3]);
            }
            l_acc[qt] += (pv[qt][0] + pv[qt][1]) + (pv[qt][2] + pv[qt][3]);
        }

        // ---- O^T += V^T P^T ----
        __builtin_amdgcn_s_setprio(1);
#pragma unroll
        for (int kb = 0; kb < 4; ++kb) {
            const short4v pb0 = __builtin_bit_cast(short4v,
                (uint2v){pack2(pv[0][kb][0], pv[0][kb][1]),
                         pack2(pv[0][kb][2], pv[0][kb][3])});
            const short4v pb1 = __builtin_bit_cast(short4v,
                (uint2v){pack2(pv[1][kb][0], pv[1][kb][1]),
                         pack2(pv[1][kb][2], pv[1][kb][3])});
            const int sl = kb * 2 + (g >> 1);
#pragma unroll
            for (int dt = 0; dt < 4; ++dt) {
                const int R = dt * 16 + q4;
                const short4v a = *(const short4v*)&lv[R * 128 +
                    ((sl ^ (R & 7)) << 4) + ((g & 1) << 3)];
                oacc[0][dt] = mfma16(a, pb0, oacc[0][dt]);
                oacc[1][dt] = mfma16(a, pb1, oacc[1][dt]);
            }
        }
        __builtin_amdgcn_s_setprio(0);

        BAR();   // all waves done reading buf[cur]
        if (tt + 2 < NT) ISSUE_KV(cur, kbeg + (tt + 2) * 64)
        cur ^= 1;
    }

    // ---- one-time cross-lane l reduction ----
    float l_run[2];
#pragma unroll
    for (int qt = 0; qt < 2; ++qt) {
        float s = (l_acc[qt][0] + l_acc[qt][1]) + (l_acc[qt][2] + l_acc[qt][3]);
        s += __shfl_xor(s, 16);
        s += __shfl_xor(s, 32);
        l_run[qt] = s;
    }

    if (!direct && g == 0) {
#pragma unroll
        for (int qt = 0; qt < 2; ++qt) {
            const size_t mrow = (size_t)split * SEQ + row0 + wid * 32 + qt * 16 + q4;
            ml[mrow * 2 + 0] = 0.0f;     // fixed m
            ml[mrow * 2 + 1] = l_run[qt];
        }
    }

    if (direct) {
        // ---- fp32 two-pass transpose, full 256B-row stores ----
        float* trans = (float*)lds;       // [64][68]
        float* outbase = (float*)opart;
#pragma unroll
        for (int qt = 0; qt < 2; ++qt) {
            __syncthreads();
            {
                const int r = wid * 16 + q4;
                const float sc = 1.0f / l_run[qt];
#pragma unroll
                for (int dt = 0; dt < 4; ++dt)
                    *(floatx4*)&trans[r * 68 + dt * 16 + g * 4] = oacc[qt][dt] * sc;
            }
            __syncthreads();
#pragma unroll
            for (int it = 0; it < 4; ++it) {
                const int r = it * 16 + (t >> 4);
                const int qrow = row0 + ((r >> 4) << 5) + qt * 16 + (r & 15);
                const floatx4 v = *(const floatx4*)&trans[r * 68 + (t & 15) * 4];
                *(floatx4*)&outbase[(size_t)qrow * 64 + (t & 15) * 4] = v;
            }
        }
    } else {
        // ---- bf16 two-pass transpose, full 128B-row stores ----
        unsigned short* transb = (unsigned short*)lds;   // [64][72] bf16
        unsigned short* outb = (unsigned short*)opart + (size_t)split * SEQ * 64;
#pragma unroll
        for (int qt = 0; qt < 2; ++qt) {
            __syncthreads();
            {
                const int r = wid * 16 + q4;
#pragma unroll
                for (int dt = 0; dt < 4; ++dt) {
                    uint2 v2;
                    v2.x = pack2(oacc[qt][dt][0], oacc[qt][dt][1]);
                    v2.y = pack2(oacc[qt][dt][2], oacc[qt][dt][3]);
                    *(uint2*)&transb[r * 72 + dt * 16 + g * 4] = v2;
                }
            }
            __syncthreads();
#pragma unroll
            for (int it = 0; it < 2; ++it) {
                const int r = it * 32 + (t >> 3);
                const int qrow = row0 + ((r >> 4) << 5) + qt * 16 + (r & 15);
                const short8 v = *(const short8*)&transb[r * 72 + (t & 7) * 8];
                *(short8*)&outb[(size_t)qrow * 64 + (t & 7) * 8] = v;
            }
        }
    }
#undef ISSUE_KV
}

// ---------------------------------------------------------------------------
// Kernel 3: combine bf16 split partials (m == 0 everywhere -> plain sums).
// out = (Σ O_s) / (Σ l_s), fp32 accumulate.  8 outputs / thread.
// ---------------------------------------------------------------------------
__global__ __launch_bounds__(256) void combine_kernel(
    const unsigned short* __restrict__ opart, const float* __restrict__ ml,
    float* __restrict__ out, int nsplit)
{
    const int i8 = (blockIdx.x * 256 + threadIdx.x) * 8;
    if (i8 >= SEQ * DOUT) return;
    const int row = i8 >> 6;

    float denom = 0.f;
    float acc[8] = {0.f, 0.f, 0.f, 0.f, 0.f, 0.f, 0.f, 0.f};
    for (int s = 0; s < nsplit; ++s) {
        denom += ml[((size_t)s * SEQ + row) * 2 + 1];
        const short8 v = *(const short8*)&opart[(size_t)s * SEQ * DOUT + i8];
#pragma unroll
        for (int j = 0; j < 8; ++j)
            acc[j] += bf2f((unsigned short)v[j]);
    }
    const float inv = 1.0f / denom;
    floatx4 o0 = {acc[0] * inv, acc[1] * inv, acc[2] * inv, acc[3] * inv};
    floatx4 o1 = {acc[4] * inv, acc[5] * inv, acc[6] * inv, acc[7] * inv};
    *(floatx4*)&out[i8] = o0;
    *(floatx4*)&out[i8 + 4] = o1;
}

// ---------------------------------------------------------------------------
extern "C" void kernel_launch(void* const* d_in, const int* in_sizes, int n_in,
                              void* d_out, int out_size, void* d_ws, size_t ws_size,
                              hipStream_t stream)
{
    const float* x  = (const float*)d_in[0];
    const float* Wq = (const float*)d_in[1];
    const float* Wk = (const float*)d_in[2];
    const float* Wv = (const float*)d_in[3];
    float* out = (float*)d_out;
    unsigned char* ws = (unsigned char*)d_ws;

    const size_t wbf_b = (size_t)192 * DIN * 2;
    const size_t qkv_b = (size_t)SEQ * 64 * 2;
    size_t off = 0;
    unsigned short* wbf  = (unsigned short*)(ws + off); off += wbf_b;
    unsigned short* qbf  = (unsigned short*)(ws + off); off += qkv_b;
    unsigned short* kbf  = (unsigned short*)(ws + off); off += qkv_b;
    unsigned short* vtbf = (unsigned short*)(ws + off); off += qkv_b;

    // per split: bf16 opart (1 MB) + fp32 ml (64 KB)
    const size_t per_split = (size_t)SEQ * 64 * 2 + (size_t)SEQ * 2 * 4;
    int nsplit = 0;
    if      (ws_size >= off + 16 * per_split) nsplit = 16;
    else if (ws_size >= off + 8 * per_split)  nsplit = 8;
    else if (ws_size >= off + 4 * per_split)  nsplit = 4;
    else if (ws_size >= off + 2 * per_split)  nsplit = 2;

    prep_w<<<72, 256, 0, stream>>>(Wq, Wk, Wv, wbf);
    qkv_mfma<<<SEQ / 32, 256, 0, stream>>>(x, wbf, qbf, kbf, vtbf);

    if (nsplit == 0) {
        flash_mfma<<<dim3(SEQ / 128, 1), 256, 0, stream>>>(
            qbf, kbf, vtbf, (void*)out, nullptr, 1, 1);
    } else {
        unsigned short* opart = (unsigned short*)(ws + off);
        float* mlp = (float*)(ws + off + (size_t)nsplit * SEQ * 64 * 2);
        flash_mfma<<<dim3(SEQ / 128, nsplit), 256, 0, stream>>>(
            qbf, kbf, vtbf, (void*)opart, mlp, nsplit, 0);
        combine_kernel<<<SEQ * DOUT / 8 / 256, 256, 0, stream>>>(
            opart, mlp, out, nsplit);
    }
}

// Round 19
// 52.996 us; speedup vs baseline: 1.1153x; 1.0792x over previous
//
#include <hip/hip_runtime.h>
#include <hip/hip_bf16.h>
#include <math.h>

#define SEQ 8192
#define DIN 768
#define DOUT 64
#define QSCALE 0.1803368801111214f   // 0.125 * log2(e)

typedef __attribute__((ext_vector_type(8))) short short8;
typedef __attribute__((ext_vector_type(4))) short short4v;
typedef __attribute__((ext_vector_type(4))) float floatx4;
typedef __attribute__((ext_vector_type(2))) unsigned int uint2v;

// ---------------------------------------------------------------------------
// helpers
// ---------------------------------------------------------------------------
__device__ __forceinline__ void gload16(const void* g, void* l) {
    __builtin_amdgcn_global_load_lds(
        (const __attribute__((address_space(1))) unsigned int*)g,
        (__attribute__((address_space(3))) unsigned int*)l, 16, 0, 0);
}

__device__ __forceinline__ unsigned pack2(float a, float b) {
    __hip_bfloat162 h = __float22bfloat162_rn(make_float2(a, b));
    return *(unsigned*)&h;
}

__device__ __forceinline__ unsigned short bfbits(float f) {
    __hip_bfloat16 h = __float2bfloat16(f);
    return *(unsigned short*)&h;
}

__device__ __forceinline__ float bf2f(unsigned short u) {
    unsigned v = ((unsigned)u) << 16;
    return *(float*)&v;
}

__device__ __forceinline__ float exp2r(float x) {
#if __has_builtin(__builtin_amdgcn_exp2f)
    return __builtin_amdgcn_exp2f(x);
#else
    float r; asm("v_exp_f32 %0, %1" : "=v"(r) : "v"(x)); return r;
#endif
}

__device__ __forceinline__ floatx4 mfma16(short4v a, short4v b, floatx4 c) {
#if __has_builtin(__builtin_amdgcn_mfma_f32_16x16x16bf16_1k)
    return __builtin_amdgcn_mfma_f32_16x16x16bf16_1k(a, b, c, 0, 0, 0);
#else
    asm("v_mfma_f32_16x16x16_bf16 %0, %1, %2, %0" : "+v"(c) : "v"(a), "v"(b));
    return c;
#endif
}

// barrier that is ALSO a compiler memory fence (raw builtin is not)
#define BAR()       asm volatile("s_barrier" ::: "memory")
#define WAIT_VM4()  asm volatile("s_waitcnt vmcnt(4)" ::: "memory")
#define WAIT_VM0()  asm volatile("s_waitcnt vmcnt(0)" ::: "memory")

// ---------------------------------------------------------------------------
// Kernel 1: QKV projection via MFMA (round-12 version, frozen).
// Inline W fp32->bf16, 3-deep x prefetch, 512 thr, 32 rows/block, grid 256.
// Out: qbf [SEQ][64] (pre-scaled QSCALE), kbf [SEQ][64], vtbf [64][SEQ].
// LDS swizzle: byte(R,c) = R*128 + (((c>>3) ^ (R&7))<<4) + (c&7)*2
// ---------------------------------------------------------------------------
__global__ __launch_bounds__(512) void qkv_mfma(
    const float* __restrict__ x,
    const float* __restrict__ Wq, const float* __restrict__ Wk,
    const float* __restrict__ Wv,
    unsigned short* __restrict__ qbf, unsigned short* __restrict__ kbf,
    unsigned short* __restrict__ vtbf)
{
    __shared__ __align__(16) unsigned char xs[2][32 * 128];    // 2 x 4 KB
    __shared__ __align__(16) unsigned char wsm[2][192 * 128];  // 2 x 24 KB

    const int t = threadIdx.x;          // 0..511
    const int l = t & 63;
    const int wid = t >> 6;             // 0..7
    const int h = wid & 1;              // row-tile (16 rows)
    const int ntb = (wid >> 1) * 3;     // nt triple base {0,3,6,9}
    const int g = l >> 4;
    const int q4 = l & 15;
    const int row0 = blockIdx.x * 32;

    const int wrow0 = (t >> 3) * 3;     // 0,3,...,189
    const int wc8   = t & 7;            // 8-col chunk
    const int xrow = t >> 4;            // 0..31
    const int xc4  = t & 15;            // 4-col chunk

    float4 wreg[3][2];
    float4 xA, xB, x0;

#define WLOAD(k0)                                                             \
    {                                                                         \
        _Pragma("unroll")                                                     \
        for (int rr = 0; rr < 3; ++rr) {                                      \
            const int row = wrow0 + rr;                                       \
            const float* wp = (row < 64)  ? &Wq[(size_t)row * DIN]            \
                           : (row < 128) ? &Wk[(size_t)(row - 64) * DIN]      \
                                         : &Wv[(size_t)(row - 128) * DIN];    \
            wreg[rr][0] = *(const float4*)&wp[(k0) + wc8 * 8];                \
            wreg[rr][1] = *(const float4*)&wp[(k0) + wc8 * 8 + 4];            \
        }                                                                     \
    }
#define WWRITE(buf)                                                           \
    {                                                                         \
        _Pragma("unroll")                                                     \
        for (int rr = 0; rr < 3; ++rr) {                                      \
            const int row = wrow0 + rr;                                       \
            uint4 v;                                                          \
            v.x = pack2(wreg[rr][0].x, wreg[rr][0].y);                        \
            v.y = pack2(wreg[rr][0].z, wreg[rr][0].w);                        \
            v.z = pack2(wreg[rr][1].x, wreg[rr][1].y);                        \
            v.w = pack2(wreg[rr][1].z, wreg[rr][1].w);                        \
            *(uint4*)&wsm[buf][row * 128 + ((wc8 ^ (row & 7)) << 4)] = v;     \
        }                                                                     \
    }
#define XLOAD(dst, k0)                                                        \
    dst = *(const float4*)&x[(size_t)(row0 + xrow) * DIN + (k0) + xc4 * 4];
#define XWRITE(buf, src)                                                      \
    {                                                                         \
        uint2 v2;                                                             \
        v2.x = pack2(src.x, src.y);                                           \
        v2.y = pack2(src.z, src.w);                                           \
        const int half = xc4 & 1, slq = xc4 >> 1;                             \
        *(uint2*)&xs[buf][xrow * 128 + ((slq ^ (xrow & 7)) << 4) + half * 8] = v2; \
    }

    floatx4 acc[3];
#pragma unroll
    for (int i = 0; i < 3; ++i) acc[i] = (floatx4){0.f, 0.f, 0.f, 0.f};

    // ---- prologue: chunk 0 staged; x chunks 1,2 + W chunk 1 in flight ----
    WLOAD(0)
    XLOAD(x0, 0)
    XLOAD(xA, 64)       // chunk 1 (odd)
    XLOAD(xB, 128)      // chunk 2 (even)
    WWRITE(0)
    XWRITE(0, x0)
    WLOAD(64)           // W chunk 1 into wreg
    __syncthreads();

#pragma unroll
    for (int kc = 0; kc < 12; ++kc) {
        const int cur = kc & 1;

        // ---- compute chunk kc from buf[cur] ----
        __builtin_amdgcn_s_setprio(1);
#pragma unroll
        for (int ks = 0; ks < 2; ++ks) {
            const int sl = g + 4 * ks;
            const int Rx = h * 16 + q4;
            const short8 a = *(const short8*)&xs[cur][Rx * 128 + ((sl ^ (Rx & 7)) << 4)];
#pragma unroll
            for (int j = 0; j < 3; ++j) {
                const int Rw = (ntb + j) * 16 + q4;
                const short8 b = *(const short8*)&wsm[cur][Rw * 128 + ((sl ^ (Rw & 7)) << 4)];
                acc[j] = __builtin_amdgcn_mfma_f32_16x16x32_bf16(a, b, acc[j], 0, 0, 0);
            }
        }
        __builtin_amdgcn_s_setprio(0);

        // ---- tail: write chunk kc+1 (regs held 2 iters), reload ahead ----
        if (kc + 1 < 12) {
            WWRITE(cur ^ 1)                       // W(kc+1)
            if ((kc + 1) & 1) { XWRITE(cur ^ 1, xA) } else { XWRITE(cur ^ 1, xB) }
            if (kc + 2 < 12) WLOAD((kc + 2) * 64) // W(kc+2), consumed next tail
            if (kc + 3 < 12) {
                if ((kc + 3) & 1) { XLOAD(xA, (kc + 3) * 64) }
                else             { XLOAD(xB, (kc + 3) * 64) }
            }
        }
        __syncthreads();
    }

    // epilogue: C layout row=(l>>4)*4+reg, col=l&15
    const int rb = row0 + h * 16 + (g << 2);
#pragma unroll
    for (int j = 0; j < 3; ++j) {
        const int nt = ntb + j;
#pragma unroll
        for (int r = 0; r < 4; ++r) {
            const float v = acc[j][r];
            const int R = rb + r;
            if (nt < 4) {
                qbf[(size_t)R * 64 + nt * 16 + q4] = bfbits(v * QSCALE);
            } else if (nt < 8) {
                kbf[(size_t)R * 64 + (nt - 4) * 16 + q4] = bfbits(v);
            } else {
                vtbf[(size_t)((nt - 8) * 16 + q4) * SEQ + R] = bfbits(v);
            }
        }
    }
#undef WLOAD
#undef WWRITE
#undef XLOAD
#undef XWRITE
}

// ---------------------------------------------------------------------------
// Kernel 2: flash attention (round-16 version, frozen).
// 32 q-rows/wave, fixed-m softmax, counted-vmcnt dbuf, bf16 partials.
// grid (SEQ/128, nsplit), 256 thr (4 waves x 32 q-rows).
// ---------------------------------------------------------------------------
__global__ __launch_bounds__(256, 4) void flash_mfma(
    const unsigned short* __restrict__ qbf,
    const unsigned short* __restrict__ kbf,
    const unsigned short* __restrict__ vtbf,
    void* __restrict__ opart,    // bf16 [nsplit][SEQ][64], or fp32 out (direct)
    float* __restrict__ ml,      // [nsplit][SEQ][2]
    int nsplit, int direct)
{
    __shared__ __align__(16) unsigned char lds[32768];
    unsigned char* lkb = lds;              // 2 x 8 KB (dbuf K)
    unsigned char* lvb = lds + 16384;      // 2 x 8 KB (dbuf V^T)

    const int t = threadIdx.x;
    const int l = t & 63;
    const int g = l >> 4;
    const int q4 = l & 15;
    const int wid = t >> 6;
    const int row0 = blockIdx.x * 128;
    const int split = blockIdx.y;
    const int chunk = SEQ / nsplit;
    const int kbeg = split * chunk;
    const int NT = chunk / 64;

#define ISSUE_KV(buf, kt)                                                     \
    {                                                                         \
        const int Rr = l >> 3;                                                \
        const int sl = (l & 7) ^ Rr;                                          \
        _Pragma("unroll")                                                     \
        for (int ss = 0; ss < 2; ++ss) {                                      \
            const int s = wid * 2 + ss;                                       \
            const int R = 8 * s + Rr;                                         \
            gload16(&kbf[(size_t)((kt) + R) * 64 + sl * 8],                   \
                    lkb + (buf) * 8192 + s * 1024);                           \
            gload16(&vtbf[(size_t)R * SEQ + (kt) + sl * 8],                   \
                    lvb + (buf) * 8192 + s * 1024);                           \
        }                                                                     \
    }

    // Q fragments: wave owns q rows [row0 + wid*32, +32)
    short8 qf[2][2];
#pragma unroll
    for (int qt = 0; qt < 2; ++qt)
#pragma unroll
        for (int ks = 0; ks < 2; ++ks)
            qf[qt][ks] = *(const short8*)&qbf[
                (size_t)(row0 + wid * 32 + qt * 16 + q4) * 64 + (g + 4 * ks) * 8];

    // prologue: tiles 0 and 1 in flight
    ISSUE_KV(0, kbeg)
    if (NT > 1) ISSUE_KV(1, kbeg + 64)

    floatx4 oacc[2][4];
#pragma unroll
    for (int i = 0; i < 2; ++i)
#pragma unroll
        for (int j = 0; j < 4; ++j) oacc[i][j] = (floatx4){0.f, 0.f, 0.f, 0.f};
    floatx4 l_acc[2] = {(floatx4){0.f, 0.f, 0.f, 0.f},
                        (floatx4){0.f, 0.f, 0.f, 0.f}};

    int cur = 0;
    for (int tt = 0; tt < NT; ++tt) {
        if (tt + 1 < NT) { WAIT_VM4(); } else { WAIT_VM0(); }
        BAR();   // tile tt staged for all waves

        const unsigned char* lk = lkb + cur * 8192;
        const unsigned char* lv = lvb + cur * 8192;

        // ---- S^T = K Q^T ----
        floatx4 sacc[2][4];
#pragma unroll
        for (int i = 0; i < 2; ++i)
#pragma unroll
            for (int j = 0; j < 4; ++j) sacc[i][j] = (floatx4){0.f, 0.f, 0.f, 0.f};
        __builtin_amdgcn_s_setprio(1);
#pragma unroll
        for (int ks = 0; ks < 2; ++ks) {
            const int sl = g + 4 * ks;
#pragma unroll
            for (int nt = 0; nt < 4; ++nt) {
                const int R = nt * 16 + q4;
                const short8 kf = *(const short8*)&lk[R * 128 + ((sl ^ (R & 7)) << 4)];
                sacc[0][nt] = __builtin_amdgcn_mfma_f32_16x16x32_bf16(kf, qf[0][ks], sacc[0][nt], 0, 0, 0);
                sacc[1][nt] = __builtin_amdgcn_mfma_f32_16x16x32_bf16(kf, qf[1][ks], sacc[1][nt], 0, 0, 0);
            }
        }
        __builtin_amdgcn_s_setprio(0);

        // ---- fixed-m softmax: p = 2^s directly ----
        floatx4 pv[2][4];
#pragma unroll
        for (int qt = 0; qt < 2; ++qt) {
#pragma unroll
            for (int nt = 0; nt < 4; ++nt) {
                pv[qt][nt][0] = exp2r(sacc[qt][nt][0]);
                pv[qt][nt][1] = exp2r(sacc[qt][nt][1]);
                pv[qt][nt][2] = exp2r(sacc[qt][nt][2]);
                pv[qt][nt][3] = exp2r(sacc[qt][nt][3]);
            }
            l_acc[qt] += (pv[qt][0] + pv[qt][1]) + (pv[qt][2] + pv[qt][3]);
        }

        // ---- O^T += V^T P^T ----
        __builtin_amdgcn_s_setprio(1);
#pragma unroll
        for (int kb = 0; kb < 4; ++kb) {
            const short4v pb0 = __builtin_bit_cast(short4v,
                (uint2v){pack2(pv[0][kb][0], pv[0][kb][1]),
                         pack2(pv[0][kb][2], pv[0][kb][3])});
            const short4v pb1 = __builtin_bit_cast(short4v,
                (uint2v){pack2(pv[1][kb][0], pv[1][kb][1]),
                         pack2(pv[1][kb][2], pv[1][kb][3])});
            const int sl = kb * 2 + (g >> 1);
#pragma unroll
            for (int dt = 0; dt < 4; ++dt) {
                const int R = dt * 16 + q4;
                const short4v a = *(const short4v*)&lv[R * 128 +
                    ((sl ^ (R & 7)) << 4) + ((g & 1) << 3)];
                oacc[0][dt] = mfma16(a, pb0, oacc[0][dt]);
                oacc[1][dt] = mfma16(a, pb1, oacc[1][dt]);
            }
        }
        __builtin_amdgcn_s_setprio(0);

        BAR();   // all waves done reading buf[cur]
        if (tt + 2 < NT) ISSUE_KV(cur, kbeg + (tt + 2) * 64)
        cur ^= 1;
    }

    // ---- one-time cross-lane l reduction ----
    float l_run[2];
#pragma unroll
    for (int qt = 0; qt < 2; ++qt) {
        float s = (l_acc[qt][0] + l_acc[qt][1]) + (l_acc[qt][2] + l_acc[qt][3]);
        s += __shfl_xor(s, 16);
        s += __shfl_xor(s, 32);
        l_run[qt] = s;
    }

    if (!direct && g == 0) {
#pragma unroll
        for (int qt = 0; qt < 2; ++qt) {
            const size_t mrow = (size_t)split * SEQ + row0 + wid * 32 + qt * 16 + q4;
            ml[mrow * 2 + 0] = 0.0f;     // fixed m
            ml[mrow * 2 + 1] = l_run[qt];
        }
    }

    if (direct) {
        // ---- fp32 two-pass transpose, full 256B-row stores ----
        float* trans = (float*)lds;       // [64][68]
        float* outbase = (float*)opart;
#pragma unroll
        for (int qt = 0; qt < 2; ++qt) {
            __syncthreads();
            {
                const int r = wid * 16 + q4;
                const float sc = 1.0f / l_run[qt];
#pragma unroll
                for (int dt = 0; dt < 4; ++dt)
                    *(floatx4*)&trans[r * 68 + dt * 16 + g * 4] = oacc[qt][dt] * sc;
            }
            __syncthreads();
#pragma unroll
            for (int it = 0; it < 4; ++it) {
                const int r = it * 16 + (t >> 4);
                const int qrow = row0 + ((r >> 4) << 5) + qt * 16 + (r & 15);
                const floatx4 v = *(const floatx4*)&trans[r * 68 + (t & 15) * 4];
                *(floatx4*)&outbase[(size_t)qrow * 64 + (t & 15) * 4] = v;
            }
        }
    } else {
        // ---- bf16 two-pass transpose, full 128B-row stores ----
        unsigned short* transb = (unsigned short*)lds;   // [64][72] bf16
        unsigned short* outb = (unsigned short*)opart + (size_t)split * SEQ * 64;
#pragma unroll
        for (int qt = 0; qt < 2; ++qt) {
            __syncthreads();
            {
                const int r = wid * 16 + q4;
#pragma unroll
                for (int dt = 0; dt < 4; ++dt) {
                    uint2 v2;
                    v2.x = pack2(oacc[qt][dt][0], oacc[qt][dt][1]);
                    v2.y = pack2(oacc[qt][dt][2], oacc[qt][dt][3]);
                    *(uint2*)&transb[r * 72 + dt * 16 + g * 4] = v2;
                }
            }
            __syncthreads();
#pragma unroll
            for (int it = 0; it < 2; ++it) {
                const int r = it * 32 + (t >> 3);
                const int qrow = row0 + ((r >> 4) << 5) + qt * 16 + (r & 15);
                const short8 v = *(const short8*)&transb[r * 72 + (t & 7) * 8];
                *(short8*)&outb[(size_t)qrow * 64 + (t & 7) * 8] = v;
            }
        }
    }
#undef ISSUE_KV
}

// ---------------------------------------------------------------------------
// Kernel 3: combine bf16 split partials (m == 0 everywhere -> plain sums).
// out = (Σ O_s) / (Σ l_s), fp32 accumulate.  8 outputs / thread.
// ---------------------------------------------------------------------------
__global__ __launch_bounds__(256) void combine_kernel(
    const unsigned short* __restrict__ opart, const float* __restrict__ ml,
    float* __restrict__ out, int nsplit)
{
    const int i8 = (blockIdx.x * 256 + threadIdx.x) * 8;
    if (i8 >= SEQ * DOUT) return;
    const int row = i8 >> 6;

    float denom = 0.f;
    float acc[8] = {0.f, 0.f, 0.f, 0.f, 0.f, 0.f, 0.f, 0.f};
    for (int s = 0; s < nsplit; ++s) {
        denom += ml[((size_t)s * SEQ + row) * 2 + 1];
        const short8 v = *(const short8*)&opart[(size_t)s * SEQ * DOUT + i8];
#pragma unroll
        for (int j = 0; j < 8; ++j)
            acc[j] += bf2f((unsigned short)v[j]);
    }
    const float inv = 1.0f / denom;
    floatx4 o0 = {acc[0] * inv, acc[1] * inv, acc[2] * inv, acc[3] * inv};
    floatx4 o1 = {acc[4] * inv, acc[5] * inv, acc[6] * inv, acc[7] * inv};
    *(floatx4*)&out[i8] = o0;
    *(floatx4*)&out[i8 + 4] = o1;
}

// ---------------------------------------------------------------------------
extern "C" void kernel_launch(void* const* d_in, const int* in_sizes, int n_in,
                              void* d_out, int out_size, void* d_ws, size_t ws_size,
                              hipStream_t stream)
{
    const float* x  = (const float*)d_in[0];
    const float* Wq = (const float*)d_in[1];
    const float* Wk = (const float*)d_in[2];
    const float* Wv = (const float*)d_in[3];
    float* out = (float*)d_out;
    unsigned char* ws = (unsigned char*)d_ws;

    const size_t qkv_b = (size_t)SEQ * 64 * 2;
    size_t off = 0;
    unsigned short* qbf  = (unsigned short*)(ws + off); off += qkv_b;
    unsigned short* kbf  = (unsigned short*)(ws + off); off += qkv_b;
    unsigned short* vtbf = (unsigned short*)(ws + off); off += qkv_b;

    // per split: bf16 opart (1 MB) + fp32 ml (64 KB)
    const size_t per_split = (size_t)SEQ * 64 * 2 + (size_t)SEQ * 2 * 4;
    int nsplit = 0;
    if      (ws_size >= off + 16 * per_split) nsplit = 16;
    else if (ws_size >= off + 8 * per_split)  nsplit = 8;
    else if (ws_size >= off + 4 * per_split)  nsplit = 4;
    else if (ws_size >= off + 2 * per_split)  nsplit = 2;

    qkv_mfma<<<SEQ / 32, 512, 0, stream>>>(x, Wq, Wk, Wv, qbf, kbf, vtbf);

    if (nsplit == 0) {
        flash_mfma<<<dim3(SEQ / 128, 1), 256, 0, stream>>>(
            qbf, kbf, vtbf, (void*)out, nullptr, 1, 1);
    } else {
        unsigned short* opart = (unsigned short*)(ws + off);
        float* mlp = (float*)(ws + off + (size_t)nsplit * SEQ * 64 * 2);
        flash_mfma<<<dim3(SEQ / 128, nsplit), 256, 0, stream>>>(
            qbf, kbf, vtbf, (void*)opart, mlp, nsplit, 0);
        combine_kernel<<<SEQ * DOUT / 8 / 256, 256, 0, stream>>>(
            opart, mlp, out, nsplit);
    }
}